// Round 3
// baseline (431.839 us; speedup 1.0000x reference)
//
#include <hip/hip_runtime.h>
#include <hip/hip_bf16.h>

#define NB 128
#define NN 2048
#define DEG 16
#define EMBD 16
#define NL 4
#define OBSD 6154
#define HID 45
#define NOUT 15
#define KS 16
#define CH 385   // ceil(OBSD / KS)
#define LOG2E 1.44269504f

__device__ __forceinline__ float frcp(float v) { return __builtin_amdgcn_rcpf(v); }

__device__ __forceinline__ uint32_t pk_bf16(float a, float b) {
    uint32_t ua = __float_as_uint(a); ua += 0x7fffu + ((ua >> 16) & 1u);
    uint32_t ub = __float_as_uint(b); ub += 0x7fffu + ((ub >> 16) & 1u);
    return (ua >> 16) | (ub & 0xffff0000u);
}
__device__ __forceinline__ float lo_bf(uint32_t u) { return __uint_as_float(u << 16); }
__device__ __forceinline__ float hi_bf(uint32_t u) { return __uint_as_float(u & 0xffff0000u); }

__device__ __forceinline__ void ln4(const float* p, const float* g, const float* bb, float* o) {
    float m = 0.25f * (p[0] + p[1] + p[2] + p[3]);
    float var = 0.f;
#pragma unroll
    for (int j = 0; j < 4; ++j) { float d = p[j] - m; var += d * d; }
    var *= 0.25f;
    float rs = rsqrtf(var + 1e-5f);
#pragma unroll
    for (int j = 0; j < 4; ++j) o[j] = g[j] * (p[j] - m) * rs + bb[j];
}

// residual tail after attention message: Wo + LN1 + FFN + LN2 (updates hh in place)
__device__ __forceinline__ void node_tail(float* hh, const float* msg,
    const float* wo, const float* bol, const float* g1, const float* be1,
    const float* w1, const float* b1l, const float* w2, const float* b2l,
    const float* g2, const float* be2)
{
    float pre[4];
#pragma unroll
    for (int j = 0; j < 4; ++j) {
        float s = bol[j];
#pragma unroll
        for (int i = 0; i < 4; ++i) s += msg[i] * wo[i * 4 + j];
        pre[j] = hh[j] + s;
    }
    float hn[4];
    ln4(pre, g1, be1, hn);
    float mid[8];
#pragma unroll
    for (int j = 0; j < 8; ++j) {
        float s = b1l[j];
#pragma unroll
        for (int i = 0; i < 4; ++i) s += hn[i] * w1[i * 8 + j];
        mid[j] = fmaxf(s, 0.f);
    }
    float pre2[4];
#pragma unroll
    for (int j = 0; j < 4; ++j) {
        float s = b2l[j];
#pragma unroll
        for (int i = 0; i < 8; ++i) s += mid[i] * w2[i * 4 + j];
        pre2[j] = hn[j] + s;
    }
    ln4(pre2, g2, be2, hh);
}

// ===================== pair-split GAT: 2 blocks per graph =====================
__global__ __launch_bounds__(512, 4) void gat_pair_kernel(
    const float* __restrict__ x, const int* __restrict__ src,
    const int* __restrict__ agent_nodes,
    const float* __restrict__ We, const float* __restrict__ be,
    const float* __restrict__ Wq, const float* __restrict__ bq,
    const float* __restrict__ Wk, const float* __restrict__ bk,
    const float* __restrict__ Wv, const float* __restrict__ bv,
    const float* __restrict__ Wo, const float* __restrict__ bo,
    const float* __restrict__ ln1_g, const float* __restrict__ ln1_b,
    const float* __restrict__ W1, const float* __restrict__ b1,
    const float* __restrict__ W2, const float* __restrict__ b2,
    const float* __restrict__ ln2_g, const float* __restrict__ ln2_b,
    float* __restrict__ gat_out, uint4* __restrict__ kvg, int* __restrict__ flags)
{
    __shared__ uint4 kv[NN];   // full graph k,v as 8x bf16: 32 KiB
    const int bid = blockIdx.x;
    const int b = bid >> 1, half = bid & 1;
    const int tid = threadIdx.x;

    float h[2][4];
    int su[2][16];

#pragma unroll
    for (int u = 0; u < 2; ++u) {
        const int n = half * 1024 + u * 512 + tid;
        const int4* sp = reinterpret_cast<const int4*>(src + n * DEG);
#pragma unroll
        for (int t4 = 0; t4 < 4; ++t4) {
            int4 s4 = sp[t4];
            su[u][t4 * 4 + 0] = s4.x; su[u][t4 * 4 + 1] = s4.y;
            su[u][t4 * 4 + 2] = s4.z; su[u][t4 * 4 + 3] = s4.w;
        }
        const float4* xr = reinterpret_cast<const float4*>(x + ((size_t)b * NN + n) * EMBD);
        float xv[16];
#pragma unroll
        for (int t4 = 0; t4 < 4; ++t4) {
            float4 t = xr[t4];
            xv[t4 * 4 + 0] = t.x; xv[t4 * 4 + 1] = t.y;
            xv[t4 * 4 + 2] = t.z; xv[t4 * 4 + 3] = t.w;
        }
#pragma unroll
        for (int j = 0; j < 4; ++j) {
            float s = be[j];
#pragma unroll
            for (int i = 0; i < 16; ++i) s += xv[i] * We[i * 4 + j];
            h[u][j] = s;
        }
    }

    for (int l = 0; l < NL; ++l) {
        const float* wq = Wq + l * 16; const float* bql = bq + l * 4;
        const float* wk = Wk + l * 16; const float* bkl = bk + l * 4;
        const float* wv = Wv + l * 16; const float* bvl = bv + l * 4;
        uint4* kvslab = kvg + ((size_t)(l & 1) * NB + b) * NN;

        __syncthreads();   // all gathers from previous layer done before LDS overwrite
        float q2[2][4];
#pragma unroll
        for (int u = 0; u < 2; ++u) {
            const int n = half * 1024 + u * 512 + tid;
            float kk[4], vv[4];
#pragma unroll
            for (int j = 0; j < 4; ++j) {
                float sq = bql[j], sk = bkl[j], sv = bvl[j];
#pragma unroll
                for (int i = 0; i < 4; ++i) {
                    sq += h[u][i] * wq[i * 4 + j];
                    sk += h[u][i] * wk[i * 4 + j];
                    sv += h[u][i] * wv[i * 4 + j];
                }
                q2[u][j] = sq * LOG2E; kk[j] = sk; vv[j] = sv;
            }
            uint4 t = make_uint4(pk_bf16(kk[0], kk[1]), pk_bf16(kk[2], kk[3]),
                                 pk_bf16(vv[0], vv[1]), pk_bf16(vv[2], vv[3]));
            kv[n] = t;
            kvslab[n] = t;
        }
        __threadfence();       // push this thread's kvg stores to device-coherent point
        __syncthreads();       // all threads fenced
        if (tid == 0) {
            __hip_atomic_store(&flags[bid], l + 1, __ATOMIC_RELEASE, __HIP_MEMORY_SCOPE_AGENT);
            while (__hip_atomic_load(&flags[bid ^ 1], __ATOMIC_ACQUIRE, __HIP_MEMORY_SCOPE_AGENT) < l + 1)
                __builtin_amdgcn_s_sleep(2);
        }
        __syncthreads();
        __threadfence();       // acquire side: don't read stale partner data
        {
            const int pb = (1 - half) * 1024;
            kv[pb + tid]       = kvslab[pb + tid];
            kv[pb + 512 + tid] = kvslab[pb + 512 + tid];
        }
        __syncthreads();

        // --- gather + single-pass softmax, both nodes interleaved for ILP ---
        float z[2][4]  = {{0.f,0.f,0.f,0.f},{0.f,0.f,0.f,0.f}};
        float wa[2][4] = {{0.f,0.f,0.f,0.f},{0.f,0.f,0.f,0.f}};
#pragma unroll
        for (int e = 0; e < 16; ++e) {
            uint4 t0 = kv[su[0][e]];
            uint4 t1 = kv[su[1][e]];
            float p;
            p = __builtin_amdgcn_exp2f(q2[0][0] * lo_bf(t0.x)); z[0][0] += p; wa[0][0] += p * lo_bf(t0.z);
            p = __builtin_amdgcn_exp2f(q2[0][1] * hi_bf(t0.x)); z[0][1] += p; wa[0][1] += p * hi_bf(t0.z);
            p = __builtin_amdgcn_exp2f(q2[0][2] * lo_bf(t0.y)); z[0][2] += p; wa[0][2] += p * lo_bf(t0.w);
            p = __builtin_amdgcn_exp2f(q2[0][3] * hi_bf(t0.y)); z[0][3] += p; wa[0][3] += p * hi_bf(t0.w);
            p = __builtin_amdgcn_exp2f(q2[1][0] * lo_bf(t1.x)); z[1][0] += p; wa[1][0] += p * lo_bf(t1.z);
            p = __builtin_amdgcn_exp2f(q2[1][1] * hi_bf(t1.x)); z[1][1] += p; wa[1][1] += p * hi_bf(t1.z);
            p = __builtin_amdgcn_exp2f(q2[1][2] * lo_bf(t1.y)); z[1][2] += p; wa[1][2] += p * lo_bf(t1.w);
            p = __builtin_amdgcn_exp2f(q2[1][3] * hi_bf(t1.y)); z[1][3] += p; wa[1][3] += p * hi_bf(t1.w);
        }

        const float* wo = Wo + l * 16; const float* bol = bo + l * 4;
        const float* g1 = ln1_g + l * 4; const float* be1 = ln1_b + l * 4;
        const float* w1 = W1 + l * 32;  const float* b1l = b1 + l * 8;
        const float* w2 = W2 + l * 32;  const float* b2l = b2 + l * 4;
        const float* g2 = ln2_g + l * 4; const float* be2 = ln2_b + l * 4;
#pragma unroll
        for (int u = 0; u < 2; ++u) {
            float msg[4];
#pragma unroll
            for (int j = 0; j < 4; ++j) msg[j] = wa[u][j] * frcp(z[u][j] + 1e-6f);
            node_tail(h[u], msg, wo, bol, g1, be1, w1, b1l, w2, b2l, g2, be2);
        }
    }

    const int agent = agent_nodes[b];
#pragma unroll
    for (int u = 0; u < 2; ++u) {
        const int n = half * 1024 + u * 512 + tid;
        if (n == agent) {
#pragma unroll
            for (int j = 0; j < 4; ++j) gat_out[b * 4 + j] = h[u][j];
        }
    }
}

// ===================== fallback: one block per graph (round-2) =====================
__global__ __launch_bounds__(1024) void gat_single_kernel(
    const float* __restrict__ x, const int* __restrict__ src,
    const int* __restrict__ agent_nodes,
    const float* __restrict__ We, const float* __restrict__ be,
    const float* __restrict__ Wq, const float* __restrict__ bq,
    const float* __restrict__ Wk, const float* __restrict__ bk,
    const float* __restrict__ Wv, const float* __restrict__ bv,
    const float* __restrict__ Wo, const float* __restrict__ bo,
    const float* __restrict__ ln1_g, const float* __restrict__ ln1_b,
    const float* __restrict__ W1, const float* __restrict__ b1,
    const float* __restrict__ W2, const float* __restrict__ b2,
    const float* __restrict__ ln2_g, const float* __restrict__ ln2_b,
    float* __restrict__ gat_out)
{
    __shared__ uint4 kv[NN];
    const int b = blockIdx.x;
    const int tid = threadIdx.x;
    float h[2][4];
#pragma unroll
    for (int u = 0; u < 2; ++u) {
        const int n = tid + u * 1024;
        const float4* xr = reinterpret_cast<const float4*>(x + ((size_t)b * NN + n) * EMBD);
        float xv[16];
#pragma unroll
        for (int t4 = 0; t4 < 4; ++t4) {
            float4 t = xr[t4];
            xv[t4 * 4 + 0] = t.x; xv[t4 * 4 + 1] = t.y;
            xv[t4 * 4 + 2] = t.z; xv[t4 * 4 + 3] = t.w;
        }
#pragma unroll
        for (int j = 0; j < 4; ++j) {
            float s = be[j];
#pragma unroll
            for (int i = 0; i < 16; ++i) s += xv[i] * We[i * 4 + j];
            h[u][j] = s;
        }
    }
    for (int l = 0; l < NL; ++l) {
        float q2[2][4];
        const float* wq = Wq + l * 16; const float* bql = bq + l * 4;
        const float* wk = Wk + l * 16; const float* bkl = bk + l * 4;
        const float* wv = Wv + l * 16; const float* bvl = bv + l * 4;
#pragma unroll
        for (int u = 0; u < 2; ++u) {
            const int n = tid + u * 1024;
            float kk[4], vv[4];
#pragma unroll
            for (int j = 0; j < 4; ++j) {
                float sq = bql[j], sk = bkl[j], sv = bvl[j];
#pragma unroll
                for (int i = 0; i < 4; ++i) {
                    sq += h[u][i] * wq[i * 4 + j];
                    sk += h[u][i] * wk[i * 4 + j];
                    sv += h[u][i] * wv[i * 4 + j];
                }
                q2[u][j] = sq * LOG2E; kk[j] = sk; vv[j] = sv;
            }
            kv[n] = make_uint4(pk_bf16(kk[0], kk[1]), pk_bf16(kk[2], kk[3]),
                               pk_bf16(vv[0], vv[1]), pk_bf16(vv[2], vv[3]));
        }
        __syncthreads();
        const float* wo = Wo + l * 16; const float* bol = bo + l * 4;
        const float* g1 = ln1_g + l * 4; const float* be1 = ln1_b + l * 4;
        const float* w1 = W1 + l * 32;  const float* b1l = b1 + l * 8;
        const float* w2 = W2 + l * 32;  const float* b2l = b2 + l * 4;
        const float* g2 = ln2_g + l * 4; const float* be2 = ln2_b + l * 4;
#pragma unroll
        for (int u = 0; u < 2; ++u) {
            const int n = tid + u * 1024;
            const int4* sp = reinterpret_cast<const int4*>(src + n * DEG);
            float z[4] = {0.f,0.f,0.f,0.f}, wa[4] = {0.f,0.f,0.f,0.f};
#pragma unroll
            for (int eb = 0; eb < 4; ++eb) {
                int4 s4 = sp[eb];
                int sis[4] = {s4.x, s4.y, s4.z, s4.w};
#pragma unroll
                for (int e = 0; e < 4; ++e) {
                    const uint4 t = kv[sis[e]];
                    float p0 = __builtin_amdgcn_exp2f(q2[u][0] * lo_bf(t.x));
                    float p1 = __builtin_amdgcn_exp2f(q2[u][1] * hi_bf(t.x));
                    float p2 = __builtin_amdgcn_exp2f(q2[u][2] * lo_bf(t.y));
                    float p3 = __builtin_amdgcn_exp2f(q2[u][3] * hi_bf(t.y));
                    z[0] += p0; z[1] += p1; z[2] += p2; z[3] += p3;
                    wa[0] += p0 * lo_bf(t.z); wa[1] += p1 * hi_bf(t.z);
                    wa[2] += p2 * lo_bf(t.w); wa[3] += p3 * hi_bf(t.w);
                }
            }
            float msg[4];
#pragma unroll
            for (int j = 0; j < 4; ++j) msg[j] = wa[j] * frcp(z[j] + 1e-6f);
            node_tail(h[u], msg, wo, bol, g1, be1, w1, b1l, w2, b2l, g2, be2);
        }
        __syncthreads();
    }
    const int agent = agent_nodes[b];
#pragma unroll
    for (int u = 0; u < 2; ++u) {
        if (tid + u * 1024 == agent) {
#pragma unroll
            for (int j = 0; j < 4; ++j) gat_out[b * 4 + j] = h[u][j];
        }
    }
}

// --- MLP stage 1: split-K partial dot products for fc1 ---
__global__ __launch_bounds__(256) void mlp1_kernel(
    const float* __restrict__ obs, const float* __restrict__ gat,
    const float* __restrict__ oW1, float* __restrict__ partial)
{
    __shared__ float red[4][HID];
    const int blk = blockIdx.x;
    const int b = blk >> 4;
    const int ks = blk & (KS - 1);
    const int tid = threadIdx.x;
    const int w = tid >> 6, lane = tid & 63;
    const float* ob = obs + (size_t)b * OBSD;

    const int c0 = ks * CH;
    const int c1 = min(c0 + CH, OBSD);
    const int wl = (c1 - c0 + 3) >> 2;
    const int s0 = c0 + w * wl;
    const int s1 = min(s0 + wl, c1);

    if (lane < HID) {
        float a0 = 0.f, a1 = 0.f, a2 = 0.f, a3 = 0.f;
        int i = s0;
        for (; i + 4 <= s1; i += 4) {
            a0 += ob[i + 0] * oW1[(size_t)(i + 4) * HID + lane];
            a1 += ob[i + 1] * oW1[(size_t)(i + 5) * HID + lane];
            a2 += ob[i + 2] * oW1[(size_t)(i + 6) * HID + lane];
            a3 += ob[i + 3] * oW1[(size_t)(i + 7) * HID + lane];
        }
        for (; i < s1; ++i) a0 += ob[i] * oW1[(size_t)(i + 4) * HID + lane];
        if (ks == 0 && w == 0) {
#pragma unroll
            for (int k = 0; k < 4; ++k) a1 += gat[b * 4 + k] * oW1[k * HID + lane];
        }
        red[w][lane] = a0 + a1 + a2 + a3;
    }
    __syncthreads();
    if (tid < HID) {
        partial[(size_t)blk * HID + tid] =
            red[0][tid] + red[1][tid] + red[2][tid] + red[3][tid];
    }
}

// --- MLP stage 2: reduce partials, tanh, fc2, tanh, fc3 ---
__global__ __launch_bounds__(64) void mlp2_kernel(
    const float* __restrict__ partial,
    const float* __restrict__ ob1,
    const float* __restrict__ oW2, const float* __restrict__ ob2,
    const float* __restrict__ oW3, const float* __restrict__ ob3,
    float* __restrict__ out)
{
    __shared__ float hm1[HID], hm2[HID];
    const int b = blockIdx.x;
    const int tid = threadIdx.x;
    if (tid < HID) {
        float s = ob1[tid];
        const float* p = partial + (size_t)b * KS * HID;
#pragma unroll
        for (int ks = 0; ks < KS; ++ks) s += p[ks * HID + tid];
        hm1[tid] = tanhf(s);
    }
    __syncthreads();
    if (tid < HID) {
        float s = ob2[tid];
        for (int k = 0; k < HID; ++k) s += hm1[k] * oW2[k * HID + tid];
        hm2[tid] = tanhf(s);
    }
    __syncthreads();
    if (tid < NOUT) {
        float s = ob3[tid];
        for (int k = 0; k < HID; ++k) s += hm2[k] * oW3[k * NOUT + tid];
        out[(size_t)b * NOUT + tid] = s;
    }
}

extern "C" void kernel_launch(void* const* d_in, const int* in_sizes, int n_in,
                              void* d_out, int out_size, void* d_ws, size_t ws_size,
                              hipStream_t stream) {
    const float* x      = (const float*)d_in[0];
    const float* obs    = (const float*)d_in[1];
    const int*   src    = (const int*)d_in[2];
    /* d_in[3] = dst: structurally repeat(arange(N), DEG) — not needed */
    const int*   agent  = (const int*)d_in[4];
    const float* We     = (const float*)d_in[5];
    const float* be     = (const float*)d_in[6];
    const float* Wq     = (const float*)d_in[7];
    const float* bq     = (const float*)d_in[8];
    const float* Wk     = (const float*)d_in[9];
    const float* bk     = (const float*)d_in[10];
    const float* Wv     = (const float*)d_in[11];
    const float* bv     = (const float*)d_in[12];
    const float* Wo     = (const float*)d_in[13];
    const float* bo     = (const float*)d_in[14];
    const float* ln1_g  = (const float*)d_in[15];
    const float* ln1_b  = (const float*)d_in[16];
    const float* W1     = (const float*)d_in[17];
    const float* b1     = (const float*)d_in[18];
    const float* W2     = (const float*)d_in[19];
    const float* b2     = (const float*)d_in[20];
    const float* ln2_g  = (const float*)d_in[21];
    const float* ln2_b  = (const float*)d_in[22];
    const float* oW1    = (const float*)d_in[23];
    const float* ob1    = (const float*)d_in[24];
    const float* oW2    = (const float*)d_in[25];
    const float* ob2    = (const float*)d_in[26];
    const float* oW3    = (const float*)d_in[27];
    const float* ob3    = (const float*)d_in[28];

    float* out     = (float*)d_out;
    char*  ws      = (char*)d_ws;
    float* gat_out = (float*)ws;                         // 512 floats
    int*   flags   = (int*)(ws + 2048);                  // 256 ints
    float* partial = (float*)(ws + 4096);                // 128*16*45 floats
    uint4* kvg     = (uint4*)(ws + 4096 + 368640);       // 2*128*2048 uint4 = 8 MiB
    const size_t need = 4096 + 368640 + (size_t)2 * NB * NN * 16;

    if (ws_size >= need) {
        hipMemsetAsync(flags, 0, 256 * sizeof(int), stream);
        gat_pair_kernel<<<NB * 2, 512, 0, stream>>>(x, src, agent, We, be, Wq, bq, Wk, bk,
                                                    Wv, bv, Wo, bo, ln1_g, ln1_b, W1, b1,
                                                    W2, b2, ln2_g, ln2_b, gat_out, kvg, flags);
    } else {
        gat_single_kernel<<<NB, 1024, 0, stream>>>(x, src, agent, We, be, Wq, bq, Wk, bk,
                                                   Wv, bv, Wo, bo, ln1_g, ln1_b, W1, b1,
                                                   W2, b2, ln2_g, ln2_b, gat_out);
    }
    mlp1_kernel<<<NB * KS, 256, 0, stream>>>(obs, gat_out, oW1, partial);
    mlp2_kernel<<<NB, 64, 0, stream>>>(partial, ob1, oW2, ob2, oW3, ob3, out);
}

// Round 4
// 72.267 us; speedup vs baseline: 5.9756x; 5.9756x over previous
//
#include <hip/hip_runtime.h>
#include <hip/hip_bf16.h>

#define NB 128
#define NN 2048
#define DEG 16
#define EMBD 16
#define NL 4
#define OBSD 6154
#define HID 45
#define NOUT 15
#define KS 16
#define CH 385   // ceil(OBSD / KS)
#define LOG2E 1.44269504f

__device__ __forceinline__ float frcp(float v) { return __builtin_amdgcn_rcpf(v); }

__device__ __forceinline__ uint32_t pk_bf16(float a, float b) {
    uint32_t ua = __float_as_uint(a); ua += 0x7fffu + ((ua >> 16) & 1u);
    uint32_t ub = __float_as_uint(b); ub += 0x7fffu + ((ub >> 16) & 1u);
    return (ua >> 16) | (ub & 0xffff0000u);
}
__device__ __forceinline__ float lo_bf(uint32_t u) { return __uint_as_float(u << 16); }
__device__ __forceinline__ float hi_bf(uint32_t u) { return __uint_as_float(u & 0xffff0000u); }

__device__ __forceinline__ void ln4(const float* p, const float* g, const float* bb, float* o) {
    float m = 0.25f * (p[0] + p[1] + p[2] + p[3]);
    float var = 0.f;
#pragma unroll
    for (int j = 0; j < 4; ++j) { float d = p[j] - m; var += d * d; }
    var *= 0.25f;
    float rs = rsqrtf(var + 1e-5f);
#pragma unroll
    for (int j = 0; j < 4; ++j) o[j] = g[j] * (p[j] - m) * rs + bb[j];
}

// residual tail after attention message: Wo + LN1 + FFN + LN2 (updates hh in place)
__device__ __forceinline__ void node_tail(float* hh, const float* msg,
    const float* wo, const float* bol, const float* g1, const float* be1,
    const float* w1, const float* b1l, const float* w2, const float* b2l,
    const float* g2, const float* be2)
{
    float pre[4];
#pragma unroll
    for (int j = 0; j < 4; ++j) {
        float s = bol[j];
#pragma unroll
        for (int i = 0; i < 4; ++i) s += msg[i] * wo[i * 4 + j];
        pre[j] = hh[j] + s;
    }
    float hn[4];
    ln4(pre, g1, be1, hn);
    float mid[8];
#pragma unroll
    for (int j = 0; j < 8; ++j) {
        float s = b1l[j];
#pragma unroll
        for (int i = 0; i < 4; ++i) s += hn[i] * w1[i * 8 + j];
        mid[j] = fmaxf(s, 0.f);
    }
    float pre2[4];
#pragma unroll
    for (int j = 0; j < 4; ++j) {
        float s = b2l[j];
#pragma unroll
        for (int i = 0; i < 8; ++i) s += mid[i] * w2[i * 4 + j];
        pre2[j] = hn[j] + s;
    }
    ln4(pre2, g2, be2, hh);
}

// ===================== embed: h = x @ We + be =====================
__global__ __launch_bounds__(256) void embed_kernel(
    const float* __restrict__ x, const float* __restrict__ We,
    const float* __restrict__ be, float4* __restrict__ hout)
{
    const size_t n = (size_t)blockIdx.x * 256 + threadIdx.x;   // < NB*NN
    const float4* xr = reinterpret_cast<const float4*>(x + n * EMBD);
    float xv[16];
#pragma unroll
    for (int t4 = 0; t4 < 4; ++t4) {
        float4 t = xr[t4];
        xv[t4 * 4 + 0] = t.x; xv[t4 * 4 + 1] = t.y;
        xv[t4 * 4 + 2] = t.z; xv[t4 * 4 + 3] = t.w;
    }
    float o[4];
#pragma unroll
    for (int j = 0; j < 4; ++j) {
        float s = be[j];
#pragma unroll
        for (int i = 0; i < 16; ++i) s += xv[i] * We[i * 4 + j];
        o[j] = s;
    }
    hout[n] = make_float4(o[0], o[1], o[2], o[3]);
}

// ============ one GAT layer: 4 blocks/graph, duplicated kv staging ============
__global__ __launch_bounds__(512, 4) void gat_layer_kernel(
    const float4* __restrict__ hin, float4* __restrict__ hout,
    const int* __restrict__ src, const int* __restrict__ agent_nodes, int l,
    const float* __restrict__ Wq, const float* __restrict__ bq,
    const float* __restrict__ Wk, const float* __restrict__ bk,
    const float* __restrict__ Wv, const float* __restrict__ bv,
    const float* __restrict__ Wo, const float* __restrict__ bo,
    const float* __restrict__ ln1_g, const float* __restrict__ ln1_b,
    const float* __restrict__ W1, const float* __restrict__ b1,
    const float* __restrict__ W2, const float* __restrict__ b2,
    const float* __restrict__ ln2_g, const float* __restrict__ ln2_b,
    float* __restrict__ gat_out)
{
    __shared__ uint4 kv[NN];   // full-graph k,v as 8x bf16: 32 KiB
    const int blk = blockIdx.x;
    const int b = blk >> 2, qd = blk & 3;
    const int tid = threadIdx.x;
    const int own = qd * 512 + tid;

    const float* wq = Wq + l * 16; const float* bql = bq + l * 4;
    const float* wk = Wk + l * 16; const float* bkl = bk + l * 4;
    const float* wv = Wv + l * 16; const float* bvl = bv + l * 4;

    // own-node edge list
    int su[16];
    {
        const int4* sp = reinterpret_cast<const int4*>(src + own * DEG);
#pragma unroll
        for (int t4 = 0; t4 < 4; ++t4) {
            int4 s4 = sp[t4];
            su[t4 * 4 + 0] = s4.x; su[t4 * 4 + 1] = s4.y;
            su[t4 * 4 + 2] = s4.z; su[t4 * 4 + 3] = s4.w;
        }
    }

    const float4* hb = hin + (size_t)b * NN;

    // stage kv for the whole graph (duplicated across the 4 blocks of this graph)
    float4 hv[4];
#pragma unroll
    for (int c = 0; c < 4; ++c) hv[c] = hb[c * 512 + tid];
#pragma unroll
    for (int c = 0; c < 4; ++c) {
        float hh[4] = {hv[c].x, hv[c].y, hv[c].z, hv[c].w};
        float kk[4], vv[4];
#pragma unroll
        for (int j = 0; j < 4; ++j) {
            float sk = bkl[j], sv = bvl[j];
#pragma unroll
            for (int i = 0; i < 4; ++i) {
                sk += hh[i] * wk[i * 4 + j];
                sv += hh[i] * wv[i * 4 + j];
            }
            kk[j] = sk; vv[j] = sv;
        }
        kv[c * 512 + tid] = make_uint4(pk_bf16(kk[0], kk[1]), pk_bf16(kk[2], kk[3]),
                                       pk_bf16(vv[0], vv[1]), pk_bf16(vv[2], vv[3]));
    }

    // own node: residual base + prescaled q
    float4 hq4 = hb[own];
    float hh[4] = {hq4.x, hq4.y, hq4.z, hq4.w};
    float q2[4];
#pragma unroll
    for (int j = 0; j < 4; ++j) {
        float sq = bql[j];
#pragma unroll
        for (int i = 0; i < 4; ++i) sq += hh[i] * wq[i * 4 + j];
        q2[j] = sq * LOG2E;
    }
    __syncthreads();

    // gather: issue all 16 reads first for latency overlap
    uint4 t[16];
#pragma unroll
    for (int e = 0; e < 16; ++e) t[e] = kv[su[e]];

    float z[4] = {0.f, 0.f, 0.f, 0.f}, wa[4] = {0.f, 0.f, 0.f, 0.f};
#pragma unroll
    for (int e = 0; e < 16; ++e) {
        float p0 = __builtin_amdgcn_exp2f(q2[0] * lo_bf(t[e].x));
        float p1 = __builtin_amdgcn_exp2f(q2[1] * hi_bf(t[e].x));
        float p2 = __builtin_amdgcn_exp2f(q2[2] * lo_bf(t[e].y));
        float p3 = __builtin_amdgcn_exp2f(q2[3] * hi_bf(t[e].y));
        z[0] += p0; z[1] += p1; z[2] += p2; z[3] += p3;
        wa[0] += p0 * lo_bf(t[e].z); wa[1] += p1 * hi_bf(t[e].z);
        wa[2] += p2 * lo_bf(t[e].w); wa[3] += p3 * hi_bf(t[e].w);
    }

    float msg[4];
#pragma unroll
    for (int j = 0; j < 4; ++j) msg[j] = wa[j] * frcp(z[j] + 1e-6f);

    node_tail(hh, msg, Wo + l * 16, bo + l * 4, ln1_g + l * 4, ln1_b + l * 4,
              W1 + l * 32, b1 + l * 8, W2 + l * 32, b2 + l * 4,
              ln2_g + l * 4, ln2_b + l * 4);

    hout[(size_t)b * NN + own] = make_float4(hh[0], hh[1], hh[2], hh[3]);

    if (l == NL - 1) {
        const int ag = agent_nodes[b];
        if (own == ag) {
#pragma unroll
            for (int j = 0; j < 4; ++j) gat_out[b * 4 + j] = hh[j];
        }
    }
}

// ===================== fallback: one block per graph =====================
__global__ __launch_bounds__(1024) void gat_single_kernel(
    const float* __restrict__ x, const int* __restrict__ src,
    const int* __restrict__ agent_nodes,
    const float* __restrict__ We, const float* __restrict__ be,
    const float* __restrict__ Wq, const float* __restrict__ bq,
    const float* __restrict__ Wk, const float* __restrict__ bk,
    const float* __restrict__ Wv, const float* __restrict__ bv,
    const float* __restrict__ Wo, const float* __restrict__ bo,
    const float* __restrict__ ln1_g, const float* __restrict__ ln1_b,
    const float* __restrict__ W1, const float* __restrict__ b1,
    const float* __restrict__ W2, const float* __restrict__ b2,
    const float* __restrict__ ln2_g, const float* __restrict__ ln2_b,
    float* __restrict__ gat_out)
{
    __shared__ uint4 kv[NN];
    const int b = blockIdx.x;
    const int tid = threadIdx.x;
    float h[2][4];
#pragma unroll
    for (int u = 0; u < 2; ++u) {
        const int n = tid + u * 1024;
        const float4* xr = reinterpret_cast<const float4*>(x + ((size_t)b * NN + n) * EMBD);
        float xv[16];
#pragma unroll
        for (int t4 = 0; t4 < 4; ++t4) {
            float4 t = xr[t4];
            xv[t4 * 4 + 0] = t.x; xv[t4 * 4 + 1] = t.y;
            xv[t4 * 4 + 2] = t.z; xv[t4 * 4 + 3] = t.w;
        }
#pragma unroll
        for (int j = 0; j < 4; ++j) {
            float s = be[j];
#pragma unroll
            for (int i = 0; i < 16; ++i) s += xv[i] * We[i * 4 + j];
            h[u][j] = s;
        }
    }
    for (int l = 0; l < NL; ++l) {
        float q2[2][4];
        const float* wq = Wq + l * 16; const float* bql = bq + l * 4;
        const float* wk = Wk + l * 16; const float* bkl = bk + l * 4;
        const float* wv = Wv + l * 16; const float* bvl = bv + l * 4;
#pragma unroll
        for (int u = 0; u < 2; ++u) {
            const int n = tid + u * 1024;
            float kk[4], vv[4];
#pragma unroll
            for (int j = 0; j < 4; ++j) {
                float sq = bql[j], sk = bkl[j], sv = bvl[j];
#pragma unroll
                for (int i = 0; i < 4; ++i) {
                    sq += h[u][i] * wq[i * 4 + j];
                    sk += h[u][i] * wk[i * 4 + j];
                    sv += h[u][i] * wv[i * 4 + j];
                }
                q2[u][j] = sq * LOG2E; kk[j] = sk; vv[j] = sv;
            }
            kv[n] = make_uint4(pk_bf16(kk[0], kk[1]), pk_bf16(kk[2], kk[3]),
                               pk_bf16(vv[0], vv[1]), pk_bf16(vv[2], vv[3]));
        }
        __syncthreads();
        const float* wo = Wo + l * 16; const float* bol = bo + l * 4;
        const float* g1 = ln1_g + l * 4; const float* be1 = ln1_b + l * 4;
        const float* w1 = W1 + l * 32;  const float* b1l = b1 + l * 8;
        const float* w2 = W2 + l * 32;  const float* b2l = b2 + l * 4;
        const float* g2 = ln2_g + l * 4; const float* be2 = ln2_b + l * 4;
#pragma unroll
        for (int u = 0; u < 2; ++u) {
            const int n = tid + u * 1024;
            const int4* sp = reinterpret_cast<const int4*>(src + n * DEG);
            float z[4] = {0.f,0.f,0.f,0.f}, wa[4] = {0.f,0.f,0.f,0.f};
#pragma unroll
            for (int eb = 0; eb < 4; ++eb) {
                int4 s4 = sp[eb];
                int sis[4] = {s4.x, s4.y, s4.z, s4.w};
#pragma unroll
                for (int e = 0; e < 4; ++e) {
                    const uint4 t = kv[sis[e]];
                    float p0 = __builtin_amdgcn_exp2f(q2[u][0] * lo_bf(t.x));
                    float p1 = __builtin_amdgcn_exp2f(q2[u][1] * hi_bf(t.x));
                    float p2 = __builtin_amdgcn_exp2f(q2[u][2] * lo_bf(t.y));
                    float p3 = __builtin_amdgcn_exp2f(q2[u][3] * hi_bf(t.y));
                    z[0] += p0; z[1] += p1; z[2] += p2; z[3] += p3;
                    wa[0] += p0 * lo_bf(t.z); wa[1] += p1 * hi_bf(t.z);
                    wa[2] += p2 * lo_bf(t.w); wa[3] += p3 * hi_bf(t.w);
                }
            }
            float msg[4];
#pragma unroll
            for (int j = 0; j < 4; ++j) msg[j] = wa[j] * frcp(z[j] + 1e-6f);
            node_tail(h[u], msg, wo, bol, g1, be1, w1, b1l, w2, b2l, g2, be2);
        }
        __syncthreads();
    }
    const int agent = agent_nodes[b];
#pragma unroll
    for (int u = 0; u < 2; ++u) {
        if (tid + u * 1024 == agent) {
#pragma unroll
            for (int j = 0; j < 4; ++j) gat_out[b * 4 + j] = h[u][j];
        }
    }
}

// --- MLP stage 1: split-K partial dot products for fc1 ---
__global__ __launch_bounds__(256) void mlp1_kernel(
    const float* __restrict__ obs, const float* __restrict__ gat,
    const float* __restrict__ oW1, float* __restrict__ partial)
{
    __shared__ float red[4][HID];
    const int blk = blockIdx.x;
    const int b = blk >> 4;
    const int ks = blk & (KS - 1);
    const int tid = threadIdx.x;
    const int w = tid >> 6, lane = tid & 63;
    const float* ob = obs + (size_t)b * OBSD;

    const int c0 = ks * CH;
    const int c1 = min(c0 + CH, OBSD);
    const int wl = (c1 - c0 + 3) >> 2;
    const int s0 = c0 + w * wl;
    const int s1 = min(s0 + wl, c1);

    if (lane < HID) {
        float a0 = 0.f, a1 = 0.f, a2 = 0.f, a3 = 0.f;
        int i = s0;
        for (; i + 4 <= s1; i += 4) {
            a0 += ob[i + 0] * oW1[(size_t)(i + 4) * HID + lane];
            a1 += ob[i + 1] * oW1[(size_t)(i + 5) * HID + lane];
            a2 += ob[i + 2] * oW1[(size_t)(i + 6) * HID + lane];
            a3 += ob[i + 3] * oW1[(size_t)(i + 7) * HID + lane];
        }
        for (; i < s1; ++i) a0 += ob[i] * oW1[(size_t)(i + 4) * HID + lane];
        if (ks == 0 && w == 0) {
#pragma unroll
            for (int k = 0; k < 4; ++k) a1 += gat[b * 4 + k] * oW1[k * HID + lane];
        }
        red[w][lane] = a0 + a1 + a2 + a3;
    }
    __syncthreads();
    if (tid < HID) {
        partial[(size_t)blk * HID + tid] =
            red[0][tid] + red[1][tid] + red[2][tid] + red[3][tid];
    }
}

// --- MLP stage 2: reduce partials, tanh, fc2, tanh, fc3 ---
__global__ __launch_bounds__(64) void mlp2_kernel(
    const float* __restrict__ partial,
    const float* __restrict__ ob1,
    const float* __restrict__ oW2, const float* __restrict__ ob2,
    const float* __restrict__ oW3, const float* __restrict__ ob3,
    float* __restrict__ out)
{
    __shared__ float hm1[HID], hm2[HID];
    const int b = blockIdx.x;
    const int tid = threadIdx.x;
    if (tid < HID) {
        float s = ob1[tid];
        const float* p = partial + (size_t)b * KS * HID;
#pragma unroll
        for (int ks = 0; ks < KS; ++ks) s += p[ks * HID + tid];
        hm1[tid] = tanhf(s);
    }
    __syncthreads();
    if (tid < HID) {
        float s = ob2[tid];
        for (int k = 0; k < HID; ++k) s += hm1[k] * oW2[k * HID + tid];
        hm2[tid] = tanhf(s);
    }
    __syncthreads();
    if (tid < NOUT) {
        float s = ob3[tid];
        for (int k = 0; k < HID; ++k) s += hm2[k] * oW3[k * NOUT + tid];
        out[(size_t)b * NOUT + tid] = s;
    }
}

extern "C" void kernel_launch(void* const* d_in, const int* in_sizes, int n_in,
                              void* d_out, int out_size, void* d_ws, size_t ws_size,
                              hipStream_t stream) {
    const float* x      = (const float*)d_in[0];
    const float* obs    = (const float*)d_in[1];
    const int*   src    = (const int*)d_in[2];
    /* d_in[3] = dst: structurally repeat(arange(N), DEG) — not needed */
    const int*   agent  = (const int*)d_in[4];
    const float* We     = (const float*)d_in[5];
    const float* be     = (const float*)d_in[6];
    const float* Wq     = (const float*)d_in[7];
    const float* bq     = (const float*)d_in[8];
    const float* Wk     = (const float*)d_in[9];
    const float* bk     = (const float*)d_in[10];
    const float* Wv     = (const float*)d_in[11];
    const float* bv     = (const float*)d_in[12];
    const float* Wo     = (const float*)d_in[13];
    const float* bo     = (const float*)d_in[14];
    const float* ln1_g  = (const float*)d_in[15];
    const float* ln1_b  = (const float*)d_in[16];
    const float* W1     = (const float*)d_in[17];
    const float* b1     = (const float*)d_in[18];
    const float* W2     = (const float*)d_in[19];
    const float* b2     = (const float*)d_in[20];
    const float* ln2_g  = (const float*)d_in[21];
    const float* ln2_b  = (const float*)d_in[22];
    const float* oW1    = (const float*)d_in[23];
    const float* ob1    = (const float*)d_in[24];
    const float* oW2    = (const float*)d_in[25];
    const float* ob2    = (const float*)d_in[26];
    const float* oW3    = (const float*)d_in[27];
    const float* ob3    = (const float*)d_in[28];

    float* out = (float*)d_out;
    char*  ws  = (char*)d_ws;

    const size_t hbytes = (size_t)NB * NN * 16;          // 4 MiB per h buffer
    const size_t need   = 2 * hbytes + 2048 + 368640;

    if (ws_size >= need) {
        float4* hA      = (float4*)ws;
        float4* hB      = (float4*)(ws + hbytes);
        float*  gat_out = (float*)(ws + 2 * hbytes);
        float*  partial = (float*)(ws + 2 * hbytes + 2048);

        embed_kernel<<<NB * NN / 256, 256, 0, stream>>>(x, We, be, hA);
        float4* hi = hA; float4* ho = hB;
        for (int l = 0; l < NL; ++l) {
            gat_layer_kernel<<<NB * 4, 512, 0, stream>>>(hi, ho, src, agent, l,
                Wq, bq, Wk, bk, Wv, bv, Wo, bo, ln1_g, ln1_b, W1, b1, W2, b2,
                ln2_g, ln2_b, gat_out);
            float4* t = hi; hi = ho; ho = t;
        }
        mlp1_kernel<<<NB * KS, 256, 0, stream>>>(obs, gat_out, oW1, partial);
        mlp2_kernel<<<NB, 64, 0, stream>>>(partial, ob1, oW2, ob2, oW3, ob3, out);
    } else {
        float* gat_out = (float*)ws;
        float* partial = (float*)(ws + 2048);
        gat_single_kernel<<<NB, 1024, 0, stream>>>(x, src, agent, We, be, Wq, bq, Wk, bk,
                                                   Wv, bv, Wo, bo, ln1_g, ln1_b, W1, b1,
                                                   W2, b2, ln2_g, ln2_b, gat_out);
        mlp1_kernel<<<NB * KS, 256, 0, stream>>>(obs, gat_out, oW1, partial);
        mlp2_kernel<<<NB, 64, 0, stream>>>(partial, ob1, oW2, ob2, oW3, ob3, out);
    }
}

// Round 5
// 62.082 us; speedup vs baseline: 6.9559x; 1.1640x over previous
//
#include <hip/hip_runtime.h>
#include <hip/hip_bf16.h>

#define NB 128
#define NN 2048
#define DEG 16
#define EMBD 16
#define NL 4
#define OBSD 6154
#define HID 45
#define NOUT 15
#define KS 16
#define CH 385   // ceil(OBSD / KS)
#define LOG2E 1.44269504f

__device__ __forceinline__ float frcp(float v) { return __builtin_amdgcn_rcpf(v); }

__device__ __forceinline__ uint32_t pk_bf16(float a, float b) {
    uint32_t ua = __float_as_uint(a); ua += 0x7fffu + ((ua >> 16) & 1u);
    uint32_t ub = __float_as_uint(b); ub += 0x7fffu + ((ub >> 16) & 1u);
    return (ua >> 16) | (ub & 0xffff0000u);
}
__device__ __forceinline__ float lo_bf(uint32_t u) { return __uint_as_float(u << 16); }
__device__ __forceinline__ float hi_bf(uint32_t u) { return __uint_as_float(u & 0xffff0000u); }

__device__ __forceinline__ void ln4(const float* p, const float* g, const float* bb, float* o) {
    float m = 0.25f * (p[0] + p[1] + p[2] + p[3]);
    float var = 0.f;
#pragma unroll
    for (int j = 0; j < 4; ++j) { float d = p[j] - m; var += d * d; }
    var *= 0.25f;
    float rs = rsqrtf(var + 1e-5f);
#pragma unroll
    for (int j = 0; j < 4; ++j) o[j] = g[j] * (p[j] - m) * rs + bb[j];
}

// residual tail after attention message: Wo + LN1 + FFN + LN2 (updates hh in place)
__device__ __forceinline__ void node_tail(float* hh, const float* msg,
    const float* wo, const float* bol, const float* g1, const float* be1,
    const float* w1, const float* b1l, const float* w2, const float* b2l,
    const float* g2, const float* be2)
{
    float pre[4];
#pragma unroll
    for (int j = 0; j < 4; ++j) {
        float s = bol[j];
#pragma unroll
        for (int i = 0; i < 4; ++i) s += msg[i] * wo[i * 4 + j];
        pre[j] = hh[j] + s;
    }
    float hn[4];
    ln4(pre, g1, be1, hn);
    float mid[8];
#pragma unroll
    for (int j = 0; j < 8; ++j) {
        float s = b1l[j];
#pragma unroll
        for (int i = 0; i < 4; ++i) s += hn[i] * w1[i * 8 + j];
        mid[j] = fmaxf(s, 0.f);
    }
    float pre2[4];
#pragma unroll
    for (int j = 0; j < 4; ++j) {
        float s = b2l[j];
#pragma unroll
        for (int i = 0; i < 8; ++i) s += mid[i] * w2[i * 4 + j];
        pre2[j] = hn[j] + s;
    }
    ln4(pre2, g2, be2, hh);
}

// ====== one GAT layer: 2 blocks/graph (1 CU each), embed fused into l==0 ======
__global__ __launch_bounds__(1024, 4) void gat_layer_kernel(
    const float* __restrict__ x,
    const float4* __restrict__ hin, float4* __restrict__ hout,
    const int* __restrict__ src, const int* __restrict__ agent_nodes, const int l,
    const float* __restrict__ We, const float* __restrict__ be,
    const float* __restrict__ Wq, const float* __restrict__ bq,
    const float* __restrict__ Wk, const float* __restrict__ bk,
    const float* __restrict__ Wv, const float* __restrict__ bv,
    const float* __restrict__ Wo, const float* __restrict__ bo,
    const float* __restrict__ ln1_g, const float* __restrict__ ln1_b,
    const float* __restrict__ W1, const float* __restrict__ b1,
    const float* __restrict__ W2, const float* __restrict__ b2,
    const float* __restrict__ ln2_g, const float* __restrict__ ln2_b,
    float* __restrict__ gat_out)
{
    __shared__ uint4 kv[NN];   // whole-graph k,v as 8x bf16: 32 KiB
    const int blk = blockIdx.x;
    const int b = blk >> 1, half = blk & 1;
    const int tid = threadIdx.x;
    const int own = half * 1024 + tid;

    // own-node edge list (issue early, overlaps with h load / proj)
    int su[16];
    {
        const int4* sp = reinterpret_cast<const int4*>(src + own * DEG);
#pragma unroll
        for (int t4 = 0; t4 < 4; ++t4) {
            int4 s4 = sp[t4];
            su[t4 * 4 + 0] = s4.x; su[t4 * 4 + 1] = s4.y;
            su[t4 * 4 + 2] = s4.z; su[t4 * 4 + 3] = s4.w;
        }
    }

    // h for this thread's two staged nodes: {tid, tid+1024}
    float hv[2][4];
    if (l == 0) {
#pragma unroll
        for (int c = 0; c < 2; ++c) {
            const float4* xr = reinterpret_cast<const float4*>(
                x + ((size_t)b * NN + c * 1024 + tid) * EMBD);
            float xv[16];
#pragma unroll
            for (int t4 = 0; t4 < 4; ++t4) {
                float4 t = xr[t4];
                xv[t4 * 4 + 0] = t.x; xv[t4 * 4 + 1] = t.y;
                xv[t4 * 4 + 2] = t.z; xv[t4 * 4 + 3] = t.w;
            }
#pragma unroll
            for (int j = 0; j < 4; ++j) {
                float s = be[j];
#pragma unroll
                for (int i = 0; i < 16; ++i) s += xv[i] * We[i * 4 + j];
                hv[c][j] = s;
            }
        }
    } else {
        const float4* hb = hin + (size_t)b * NN;
        float4 a0 = hb[tid];
        float4 a1 = hb[1024 + tid];
        hv[0][0] = a0.x; hv[0][1] = a0.y; hv[0][2] = a0.z; hv[0][3] = a0.w;
        hv[1][0] = a1.x; hv[1][1] = a1.y; hv[1][2] = a1.z; hv[1][3] = a1.w;
    }

    // stage k,v for both nodes into LDS (graph-wide; duplicated 2x across the pair)
    const float* wk = Wk + l * 16; const float* bkl = bk + l * 4;
    const float* wv = Wv + l * 16; const float* bvl = bv + l * 4;
#pragma unroll
    for (int c = 0; c < 2; ++c) {
        float kk[4], vv[4];
#pragma unroll
        for (int j = 0; j < 4; ++j) {
            float sk = bkl[j], sv = bvl[j];
#pragma unroll
            for (int i = 0; i < 4; ++i) {
                sk += hv[c][i] * wk[i * 4 + j];
                sv += hv[c][i] * wv[i * 4 + j];
            }
            kk[j] = sk; vv[j] = sv;
        }
        kv[c * 1024 + tid] = make_uint4(pk_bf16(kk[0], kk[1]), pk_bf16(kk[2], kk[3]),
                                        pk_bf16(vv[0], vv[1]), pk_bf16(vv[2], vv[3]));
    }

    // own node q (prescaled by log2e) + residual base
    float hh[4] = {hv[half][0], hv[half][1], hv[half][2], hv[half][3]};
    float q2[4];
    {
        const float* wq = Wq + l * 16; const float* bql = bq + l * 4;
#pragma unroll
        for (int j = 0; j < 4; ++j) {
            float sq = bql[j];
#pragma unroll
            for (int i = 0; i < 4; ++i) sq += hh[i] * wq[i * 4 + j];
            q2[j] = sq * LOG2E;
        }
    }
    __syncthreads();

    // gather own node's 16 edges in 4-edge chunks (16 VGPR live for t)
    float z[4] = {0.f, 0.f, 0.f, 0.f}, wa[4] = {0.f, 0.f, 0.f, 0.f};
#pragma unroll
    for (int eb = 0; eb < 4; ++eb) {
        uint4 t0 = kv[su[eb * 4 + 0]];
        uint4 t1 = kv[su[eb * 4 + 1]];
        uint4 t2 = kv[su[eb * 4 + 2]];
        uint4 t3 = kv[su[eb * 4 + 3]];
        float p;
        p = __builtin_amdgcn_exp2f(q2[0] * lo_bf(t0.x)); z[0] += p; wa[0] += p * lo_bf(t0.z);
        p = __builtin_amdgcn_exp2f(q2[1] * hi_bf(t0.x)); z[1] += p; wa[1] += p * hi_bf(t0.z);
        p = __builtin_amdgcn_exp2f(q2[2] * lo_bf(t0.y)); z[2] += p; wa[2] += p * lo_bf(t0.w);
        p = __builtin_amdgcn_exp2f(q2[3] * hi_bf(t0.y)); z[3] += p; wa[3] += p * hi_bf(t0.w);
        p = __builtin_amdgcn_exp2f(q2[0] * lo_bf(t1.x)); z[0] += p; wa[0] += p * lo_bf(t1.z);
        p = __builtin_amdgcn_exp2f(q2[1] * hi_bf(t1.x)); z[1] += p; wa[1] += p * hi_bf(t1.z);
        p = __builtin_amdgcn_exp2f(q2[2] * lo_bf(t1.y)); z[2] += p; wa[2] += p * lo_bf(t1.w);
        p = __builtin_amdgcn_exp2f(q2[3] * hi_bf(t1.y)); z[3] += p; wa[3] += p * hi_bf(t1.w);
        p = __builtin_amdgcn_exp2f(q2[0] * lo_bf(t2.x)); z[0] += p; wa[0] += p * lo_bf(t2.z);
        p = __builtin_amdgcn_exp2f(q2[1] * hi_bf(t2.x)); z[1] += p; wa[1] += p * hi_bf(t2.z);
        p = __builtin_amdgcn_exp2f(q2[2] * lo_bf(t2.y)); z[2] += p; wa[2] += p * lo_bf(t2.w);
        p = __builtin_amdgcn_exp2f(q2[3] * hi_bf(t2.y)); z[3] += p; wa[3] += p * hi_bf(t2.w);
        p = __builtin_amdgcn_exp2f(q2[0] * lo_bf(t3.x)); z[0] += p; wa[0] += p * lo_bf(t3.z);
        p = __builtin_amdgcn_exp2f(q2[1] * hi_bf(t3.x)); z[1] += p; wa[1] += p * hi_bf(t3.z);
        p = __builtin_amdgcn_exp2f(q2[2] * lo_bf(t3.y)); z[2] += p; wa[2] += p * lo_bf(t3.w);
        p = __builtin_amdgcn_exp2f(q2[3] * hi_bf(t3.y)); z[3] += p; wa[3] += p * hi_bf(t3.w);
    }

    float msg[4];
#pragma unroll
    for (int j = 0; j < 4; ++j) msg[j] = wa[j] * frcp(z[j] + 1e-6f);

    node_tail(hh, msg, Wo + l * 16, bo + l * 4, ln1_g + l * 4, ln1_b + l * 4,
              W1 + l * 32, b1 + l * 8, W2 + l * 32, b2 + l * 4,
              ln2_g + l * 4, ln2_b + l * 4);

    hout[(size_t)b * NN + own] = make_float4(hh[0], hh[1], hh[2], hh[3]);

    if (l == NL - 1) {
        if (own == agent_nodes[b]) {
#pragma unroll
            for (int j = 0; j < 4; ++j) gat_out[b * 4 + j] = hh[j];
        }
    }
}

// ===================== fallback: one block per graph =====================
__global__ __launch_bounds__(1024) void gat_single_kernel(
    const float* __restrict__ x, const int* __restrict__ src,
    const int* __restrict__ agent_nodes,
    const float* __restrict__ We, const float* __restrict__ be,
    const float* __restrict__ Wq, const float* __restrict__ bq,
    const float* __restrict__ Wk, const float* __restrict__ bk,
    const float* __restrict__ Wv, const float* __restrict__ bv,
    const float* __restrict__ Wo, const float* __restrict__ bo,
    const float* __restrict__ ln1_g, const float* __restrict__ ln1_b,
    const float* __restrict__ W1, const float* __restrict__ b1,
    const float* __restrict__ W2, const float* __restrict__ b2,
    const float* __restrict__ ln2_g, const float* __restrict__ ln2_b,
    float* __restrict__ gat_out)
{
    __shared__ uint4 kv[NN];
    const int b = blockIdx.x;
    const int tid = threadIdx.x;
    float h[2][4];
#pragma unroll
    for (int u = 0; u < 2; ++u) {
        const int n = tid + u * 1024;
        const float4* xr = reinterpret_cast<const float4*>(x + ((size_t)b * NN + n) * EMBD);
        float xv[16];
#pragma unroll
        for (int t4 = 0; t4 < 4; ++t4) {
            float4 t = xr[t4];
            xv[t4 * 4 + 0] = t.x; xv[t4 * 4 + 1] = t.y;
            xv[t4 * 4 + 2] = t.z; xv[t4 * 4 + 3] = t.w;
        }
#pragma unroll
        for (int j = 0; j < 4; ++j) {
            float s = be[j];
#pragma unroll
            for (int i = 0; i < 16; ++i) s += xv[i] * We[i * 4 + j];
            h[u][j] = s;
        }
    }
    for (int l = 0; l < NL; ++l) {
        float q2[2][4];
        const float* wq = Wq + l * 16; const float* bql = bq + l * 4;
        const float* wk = Wk + l * 16; const float* bkl = bk + l * 4;
        const float* wv = Wv + l * 16; const float* bvl = bv + l * 4;
#pragma unroll
        for (int u = 0; u < 2; ++u) {
            const int n = tid + u * 1024;
            float kk[4], vv[4];
#pragma unroll
            for (int j = 0; j < 4; ++j) {
                float sq = bql[j], sk = bkl[j], sv = bvl[j];
#pragma unroll
                for (int i = 0; i < 4; ++i) {
                    sq += h[u][i] * wq[i * 4 + j];
                    sk += h[u][i] * wk[i * 4 + j];
                    sv += h[u][i] * wv[i * 4 + j];
                }
                q2[u][j] = sq * LOG2E; kk[j] = sk; vv[j] = sv;
            }
            kv[n] = make_uint4(pk_bf16(kk[0], kk[1]), pk_bf16(kk[2], kk[3]),
                               pk_bf16(vv[0], vv[1]), pk_bf16(vv[2], vv[3]));
        }
        __syncthreads();
        const float* wo = Wo + l * 16; const float* bol = bo + l * 4;
        const float* g1 = ln1_g + l * 4; const float* be1 = ln1_b + l * 4;
        const float* w1 = W1 + l * 32;  const float* b1l = b1 + l * 8;
        const float* w2 = W2 + l * 32;  const float* b2l = b2 + l * 4;
        const float* g2 = ln2_g + l * 4; const float* be2 = ln2_b + l * 4;
#pragma unroll
        for (int u = 0; u < 2; ++u) {
            const int n = tid + u * 1024;
            const int4* sp = reinterpret_cast<const int4*>(src + n * DEG);
            float z[4] = {0.f,0.f,0.f,0.f}, wa[4] = {0.f,0.f,0.f,0.f};
#pragma unroll
            for (int eb = 0; eb < 4; ++eb) {
                int4 s4 = sp[eb];
                int sis[4] = {s4.x, s4.y, s4.z, s4.w};
#pragma unroll
                for (int e = 0; e < 4; ++e) {
                    const uint4 t = kv[sis[e]];
                    float p0 = __builtin_amdgcn_exp2f(q2[u][0] * lo_bf(t.x));
                    float p1 = __builtin_amdgcn_exp2f(q2[u][1] * hi_bf(t.x));
                    float p2 = __builtin_amdgcn_exp2f(q2[u][2] * lo_bf(t.y));
                    float p3 = __builtin_amdgcn_exp2f(q2[u][3] * hi_bf(t.y));
                    z[0] += p0; z[1] += p1; z[2] += p2; z[3] += p3;
                    wa[0] += p0 * lo_bf(t.z); wa[1] += p1 * hi_bf(t.z);
                    wa[2] += p2 * lo_bf(t.w); wa[3] += p3 * hi_bf(t.w);
                }
            }
            float msg[4];
#pragma unroll
            for (int j = 0; j < 4; ++j) msg[j] = wa[j] * frcp(z[j] + 1e-6f);
            node_tail(h[u], msg, wo, bol, g1, be1, w1, b1l, w2, b2l, g2, be2);
        }
        __syncthreads();
    }
    const int agent = agent_nodes[b];
#pragma unroll
    for (int u = 0; u < 2; ++u) {
        if (tid + u * 1024 == agent) {
#pragma unroll
            for (int j = 0; j < 4; ++j) gat_out[b * 4 + j] = h[u][j];
        }
    }
}

// --- MLP stage 1: split-K partial dot products for fc1 ---
__global__ __launch_bounds__(256) void mlp1_kernel(
    const float* __restrict__ obs, const float* __restrict__ gat,
    const float* __restrict__ oW1, float* __restrict__ partial)
{
    __shared__ float red[4][HID];
    const int blk = blockIdx.x;
    const int b = blk >> 4;
    const int ks = blk & (KS - 1);
    const int tid = threadIdx.x;
    const int w = tid >> 6, lane = tid & 63;
    const float* ob = obs + (size_t)b * OBSD;

    const int c0 = ks * CH;
    const int c1 = min(c0 + CH, OBSD);
    const int wl = (c1 - c0 + 3) >> 2;
    const int s0 = c0 + w * wl;
    const int s1 = min(s0 + wl, c1);

    if (lane < HID) {
        float a0 = 0.f, a1 = 0.f, a2 = 0.f, a3 = 0.f;
        int i = s0;
        for (; i + 4 <= s1; i += 4) {
            a0 += ob[i + 0] * oW1[(size_t)(i + 4) * HID + lane];
            a1 += ob[i + 1] * oW1[(size_t)(i + 5) * HID + lane];
            a2 += ob[i + 2] * oW1[(size_t)(i + 6) * HID + lane];
            a3 += ob[i + 3] * oW1[(size_t)(i + 7) * HID + lane];
        }
        for (; i < s1; ++i) a0 += ob[i] * oW1[(size_t)(i + 4) * HID + lane];
        if (ks == 0 && w == 0) {
#pragma unroll
            for (int k = 0; k < 4; ++k) a1 += gat[b * 4 + k] * oW1[k * HID + lane];
        }
        red[w][lane] = a0 + a1 + a2 + a3;
    }
    __syncthreads();
    if (tid < HID) {
        partial[(size_t)blk * HID + tid] =
            red[0][tid] + red[1][tid] + red[2][tid] + red[3][tid];
    }
}

// --- MLP stage 2: reduce partials, tanh, fc2, tanh, fc3 ---
__global__ __launch_bounds__(64) void mlp2_kernel(
    const float* __restrict__ partial,
    const float* __restrict__ ob1,
    const float* __restrict__ oW2, const float* __restrict__ ob2,
    const float* __restrict__ oW3, const float* __restrict__ ob3,
    float* __restrict__ out)
{
    __shared__ float hm1[HID], hm2[HID];
    const int b = blockIdx.x;
    const int tid = threadIdx.x;
    if (tid < HID) {
        float s = ob1[tid];
        const float* p = partial + (size_t)b * KS * HID;
#pragma unroll
        for (int ks = 0; ks < KS; ++ks) s += p[ks * HID + tid];
        hm1[tid] = tanhf(s);
    }
    __syncthreads();
    if (tid < HID) {
        float s = ob2[tid];
        for (int k = 0; k < HID; ++k) s += hm1[k] * oW2[k * HID + tid];
        hm2[tid] = tanhf(s);
    }
    __syncthreads();
    if (tid < NOUT) {
        float s = ob3[tid];
        for (int k = 0; k < HID; ++k) s += hm2[k] * oW3[k * NOUT + tid];
        out[(size_t)b * NOUT + tid] = s;
    }
}

extern "C" void kernel_launch(void* const* d_in, const int* in_sizes, int n_in,
                              void* d_out, int out_size, void* d_ws, size_t ws_size,
                              hipStream_t stream) {
    const float* x      = (const float*)d_in[0];
    const float* obs    = (const float*)d_in[1];
    const int*   src    = (const int*)d_in[2];
    /* d_in[3] = dst: structurally repeat(arange(N), DEG) — not needed */
    const int*   agent  = (const int*)d_in[4];
    const float* We     = (const float*)d_in[5];
    const float* be     = (const float*)d_in[6];
    const float* Wq     = (const float*)d_in[7];
    const float* bq     = (const float*)d_in[8];
    const float* Wk     = (const float*)d_in[9];
    const float* bk     = (const float*)d_in[10];
    const float* Wv     = (const float*)d_in[11];
    const float* bv     = (const float*)d_in[12];
    const float* Wo     = (const float*)d_in[13];
    const float* bo     = (const float*)d_in[14];
    const float* ln1_g  = (const float*)d_in[15];
    const float* ln1_b  = (const float*)d_in[16];
    const float* W1     = (const float*)d_in[17];
    const float* b1     = (const float*)d_in[18];
    const float* W2     = (const float*)d_in[19];
    const float* b2     = (const float*)d_in[20];
    const float* ln2_g  = (const float*)d_in[21];
    const float* ln2_b  = (const float*)d_in[22];
    const float* oW1    = (const float*)d_in[23];
    const float* ob1    = (const float*)d_in[24];
    const float* oW2    = (const float*)d_in[25];
    const float* ob2    = (const float*)d_in[26];
    const float* oW3    = (const float*)d_in[27];
    const float* ob3    = (const float*)d_in[28];

    float* out = (float*)d_out;
    char*  ws  = (char*)d_ws;

    const size_t hbytes = (size_t)NB * NN * 16;          // 4 MiB per h buffer
    const size_t need   = 2 * hbytes + 2048 + 368640;

    if (ws_size >= need) {
        float4* hA      = (float4*)ws;
        float4* hB      = (float4*)(ws + hbytes);
        float*  gat_out = (float*)(ws + 2 * hbytes);
        float*  partial = (float*)(ws + 2 * hbytes + 2048);

        float4* hi = hA; float4* ho = hB;
        for (int l = 0; l < NL; ++l) {
            gat_layer_kernel<<<NB * 2, 1024, 0, stream>>>(x, hi, ho, src, agent, l,
                We, be, Wq, bq, Wk, bk, Wv, bv, Wo, bo, ln1_g, ln1_b, W1, b1, W2, b2,
                ln2_g, ln2_b, gat_out);
            float4* t = hi; hi = ho; ho = t;
        }
        mlp1_kernel<<<NB * KS, 256, 0, stream>>>(obs, gat_out, oW1, partial);
        mlp2_kernel<<<NB, 64, 0, stream>>>(partial, ob1, oW2, ob2, oW3, ob3, out);
    } else {
        float* gat_out = (float*)ws;
        float* partial = (float*)(ws + 2048);
        gat_single_kernel<<<NB, 1024, 0, stream>>>(x, src, agent, We, be, Wq, bq, Wk, bk,
                                                   Wv, bv, Wo, bo, ln1_g, ln1_b, W1, b1,
                                                   W2, b2, ln2_g, ln2_b, gat_out);
        mlp1_kernel<<<NB * KS, 256, 0, stream>>>(obs, gat_out, oW1, partial);
        mlp2_kernel<<<NB, 64, 0, stream>>>(partial, ob1, oW2, ob2, oW3, ob3, out);
    }
}